// Round 1
// baseline (1037.525 us; speedup 1.0000x reference)
//
#include <hip/hip_runtime.h>
#include <stdint.h>

#define NUM_SEQS 4
#define SEQ_LEN  4096
#define HIDDEN   2048
#define CONV_DIM 2048
#define NTOK     (NUM_SEQS * SEQ_LEN)
#define N3D      (3 * CONV_DIM)

typedef unsigned short u16;
typedef unsigned int   u32;
typedef __bf16 bf16x8 __attribute__((ext_vector_type(8)));
typedef float  f32x4  __attribute__((ext_vector_type(4)));

__device__ __forceinline__ u16 f2bf(float f) {
  union { float f; u32 u; } v; v.f = f;
  u32 u = v.u;
  u += 0x7fffu + ((u >> 16) & 1u);   // round-to-nearest-even
  return (u16)(u >> 16);
}

__device__ __forceinline__ void async16(const void* g, void* l) {
  __builtin_amdgcn_global_load_lds(
      (const __attribute__((address_space(1))) u32*)g,
      (__attribute__((address_space(3))) u32*)l, 16, 0, 0);
}

// ---------------- fp32 -> bf16 cast (vectorized) ----------------
__global__ __launch_bounds__(256) void cast_f32_bf16(
    const float* __restrict__ in, u16* __restrict__ out, int n4)
{
  int i = blockIdx.x * 256 + threadIdx.x;
  if (i >= n4) return;
  float4 f = ((const float4*)in)[i];
  ushort4 o;
  o.x = f2bf(f.x); o.y = f2bf(f.y); o.z = f2bf(f.z); o.w = f2bf(f.w);
  ((ushort4*)out)[i] = o;
}

// ---------------- bf16 GEMM, C = A[M,K] * B[N,K]^T ----------------
// m97 structure: 128x128 tile, BK=32, 4 waves of 4x4 16x16x32 MFMA tiles,
// global_load_lds width=16 staging, 2-barrier K-loop.
template<bool OUT_BF16>
__global__ __launch_bounds__(256) void gemm_bt(
    const u16* __restrict__ A, const u16* __restrict__ B, void* __restrict__ Cv,
    const int M, const int N, const int K)
{
  __shared__ u16 sA[128 * 32];
  __shared__ u16 sB[128 * 32];

  const int tid  = threadIdx.x;
  const int lane = tid & 63;
  const int wave = tid >> 6;
  const int quad = lane >> 4;
  const int l16  = lane & 15;
  const int wr   = (wave >> 1) * 64;   // wave row offset in tile
  const int wc   = (wave & 1) * 64;    // wave col offset in tile
  const int mBase = blockIdx.y * 128;
  const int nBase = blockIdx.x * 128;

  // staging: 512 chunks of 16B per tile; thread handles chunks tid and tid+256
  const int c0 = tid, c1 = tid + 256;
  const u16* Ag0 = A + (size_t)(mBase + (c0 >> 2)) * K + (c0 & 3) * 8;
  const u16* Ag1 = A + (size_t)(mBase + (c1 >> 2)) * K + (c1 & 3) * 8;
  const u16* Bg0 = B + (size_t)(nBase + (c0 >> 2)) * K + (c0 & 3) * 8;
  const u16* Bg1 = B + (size_t)(nBase + (c1 >> 2)) * K + (c1 & 3) * 8;

  f32x4 zero = {0.f, 0.f, 0.f, 0.f};
  f32x4 acc[4][4];
#pragma unroll
  for (int i = 0; i < 4; ++i)
#pragma unroll
    for (int j = 0; j < 4; ++j) acc[i][j] = zero;

  for (int k0 = 0; k0 < K; k0 += 32) {
    async16(Ag0 + k0, &sA[c0 * 8]);
    async16(Ag1 + k0, &sA[c1 * 8]);
    async16(Bg0 + k0, &sB[c0 * 8]);
    async16(Bg1 + k0, &sB[c1 * 8]);
    __syncthreads();   // compiler emits s_waitcnt vmcnt(0) before s_barrier

    bf16x8 af[4], bfv[4];
#pragma unroll
    for (int t = 0; t < 4; ++t) {
      af[t]  = *(const bf16x8*)&sA[(wr + t * 16 + l16) * 32 + quad * 8];
      bfv[t] = *(const bf16x8*)&sB[(wc + t * 16 + l16) * 32 + quad * 8];
    }
#pragma unroll
    for (int i = 0; i < 4; ++i)
#pragma unroll
      for (int j = 0; j < 4; ++j)
        acc[i][j] = __builtin_amdgcn_mfma_f32_16x16x32_bf16(af[i], bfv[j], acc[i][j], 0, 0, 0);
    __syncthreads();
  }

  // epilogue: C/D layout col=lane&15, row=quad*4+reg  (m89/m91-verified)
#pragma unroll
  for (int i = 0; i < 4; ++i) {
#pragma unroll
    for (int j = 0; j < 4; ++j) {
      const int col = nBase + wc + j * 16 + l16;
#pragma unroll
      for (int r = 0; r < 4; ++r) {
        const int row = mBase + wr + i * 16 + quad * 4 + r;
        if (OUT_BF16)
          ((u16*)Cv)[(size_t)row * N + col] = f2bf(acc[i][j][r]);
        else
          ((float*)Cv)[(size_t)row * N + col] = acc[i][j][r];
      }
    }
  }
}

// ---------------- causal depthwise conv (K=4) + gating ----------------
// bcx: [NTOK, 6144] bf16 (cols: b | c | x). Produces y=[NTOK,2048] bf16 and
// conv states (last 3 bx rows per seq) fp32 into d_out tail.
#define TT 32
__global__ __launch_bounds__(256) void conv_gate(
    const u16* __restrict__ bcx, const float* __restrict__ convw,
    u16* __restrict__ y, float* __restrict__ states)
{
  const int tid = threadIdx.x;
  const int d8  = tid * 8;            // 8 channels per thread, 256 thr = 2048
  const int s   = blockIdx.y;
  const int t0  = blockIdx.x * TT;

  float w0[8], w1[8], w2[8], w3[8];
#pragma unroll
  for (int j = 0; j < 8; ++j) {
    float4 wv = *(const float4*)&convw[(d8 + j) * 4];
    w0[j] = wv.x; w1[j] = wv.y; w2[j] = wv.z; w3[j] = wv.w;
  }

  float win0[8], win1[8], win2[8];    // bx at t-3, t-2, t-1
  if (t0 == 0) {
#pragma unroll
    for (int j = 0; j < 8; ++j) { win0[j] = 0.f; win1[j] = 0.f; win2[j] = 0.f; }
  } else {
    const u16* r0 = bcx + (size_t)(s * SEQ_LEN + t0 - 3) * N3D + d8;
    bf16x8 b0 = *(const bf16x8*)(r0);
    bf16x8 x0 = *(const bf16x8*)(r0 + 2 * CONV_DIM);
    bf16x8 b1 = *(const bf16x8*)(r0 + N3D);
    bf16x8 x1 = *(const bf16x8*)(r0 + N3D + 2 * CONV_DIM);
    bf16x8 b2 = *(const bf16x8*)(r0 + 2 * N3D);
    bf16x8 x2 = *(const bf16x8*)(r0 + 2 * N3D + 2 * CONV_DIM);
#pragma unroll
    for (int j = 0; j < 8; ++j) {
      win0[j] = (float)b0[j] * (float)x0[j];
      win1[j] = (float)b1[j] * (float)x1[j];
      win2[j] = (float)b2[j] * (float)x2[j];
    }
  }

  for (int t = t0; t < t0 + TT; ++t) {
    const u16* row = bcx + (size_t)(s * SEQ_LEN + t) * N3D + d8;
    bf16x8 bv = *(const bf16x8*)row;
    bf16x8 cv = *(const bf16x8*)(row + CONV_DIM);
    bf16x8 xv = *(const bf16x8*)(row + 2 * CONV_DIM);
    float bx[8];
#pragma unroll
    for (int j = 0; j < 8; ++j) bx[j] = (float)bv[j] * (float)xv[j];

    u32 pk[4];
#pragma unroll
    for (int j = 0; j < 4; ++j) {
      const int a = 2 * j, b = 2 * j + 1;
      float ya = (float)cv[a] * (w0[a]*win0[a] + w1[a]*win1[a] + w2[a]*win2[a] + w3[a]*bx[a]);
      float yb = (float)cv[b] * (w0[b]*win0[b] + w1[b]*win1[b] + w2[b]*win2[b] + w3[b]*bx[b]);
      pk[j] = (u32)f2bf(ya) | ((u32)f2bf(yb) << 16);
    }
    uint4 o; o.x = pk[0]; o.y = pk[1]; o.z = pk[2]; o.w = pk[3];
    *(uint4*)&y[(size_t)(s * SEQ_LEN + t) * CONV_DIM + d8] = o;

    if (t >= SEQ_LEN - 3) {
      float* st = states + (size_t)(s * 3 + (t - (SEQ_LEN - 3))) * CONV_DIM + d8;
      float4 s0; s0.x = bx[0]; s0.y = bx[1]; s0.z = bx[2]; s0.w = bx[3];
      float4 s1; s1.x = bx[4]; s1.y = bx[5]; s1.z = bx[6]; s1.w = bx[7];
      *(float4*)st = s0;
      *(float4*)(st + 4) = s1;
    }
#pragma unroll
    for (int j = 0; j < 8; ++j) { win0[j] = win1[j]; win1[j] = win2[j]; win2[j] = bx[j]; }
  }
}

// ---------------- launch ----------------
extern "C" void kernel_launch(void* const* d_in, const int* in_sizes, int n_in,
                              void* d_out, int out_size, void* d_ws, size_t ws_size,
                              hipStream_t stream)
{
  const float* hidden = (const float*)d_in[0];  // [16384, 2048]
  const float* w_in   = (const float*)d_in[1];  // [6144, 2048]
  const float* convw  = (const float*)d_in[2];  // [2048, 1, 4]
  const float* w_out  = (const float*)d_in[3];  // [2048, 2048]

  char* ws = (char*)d_ws;
  u16* hb  = (u16*)(ws);                          // 33554432 elems (67.1 MB)
  u16* wib = (u16*)(ws + (size_t)67108864);       // 12582912 elems (25.2 MB)
  u16* wob = (u16*)(ws + (size_t)92274688);       //  4194304 elems ( 8.4 MB)
  u16* bcx = (u16*)(ws + (size_t)100663296);      // 16384*6144 elems (201 MB)
  u16* yb  = (u16*)(ws + (size_t)301989888);      // 33554432 elems (67.1 MB)

  float* out    = (float*)d_out;                  // [16384, 2048] fp32
  float* states = out + (size_t)NTOK * HIDDEN;    // [4, 3, 2048] fp32

  cast_f32_bf16<<<32768, 256, 0, stream>>>(hidden, hb, 8388608);
  cast_f32_bf16<<<12288, 256, 0, stream>>>(w_in,  wib, 3145728);
  cast_f32_bf16<<<4096,  256, 0, stream>>>(w_out, wob, 1048576);

  // bcx[N,6144] = hidden @ w_in^T  (bf16 out)
  gemm_bt<true><<<dim3(N3D / 128, NTOK / 128), 256, 0, stream>>>(
      hb, wib, bcx, NTOK, N3D, HIDDEN);

  // depthwise conv + gates -> y bf16, states fp32
  conv_gate<<<dim3(SEQ_LEN / TT, NUM_SEQS), 256, 0, stream>>>(bcx, convw, yb, states);

  // out[N,2048] = y @ w_out^T  (fp32 out)
  gemm_bt<false><<<dim3(CONV_DIM / 128, NTOK / 128), 256, 0, stream>>>(
      yb, wob, out, NTOK, CONV_DIM, CONV_DIM);
}

// Round 2
// 1034.853 us; speedup vs baseline: 1.0026x; 1.0026x over previous
//
#include <hip/hip_runtime.h>
#include <stdint.h>

#define NUM_SEQS 4
#define SEQ_LEN  4096
#define HIDDEN   2048
#define CONV_DIM 2048
#define NTOK     (NUM_SEQS * SEQ_LEN)
#define N3D      (3 * CONV_DIM)

typedef unsigned short u16;
typedef unsigned int   u32;
typedef __bf16 bf16x8 __attribute__((ext_vector_type(8)));
typedef float  f32x4  __attribute__((ext_vector_type(4)));

__device__ __forceinline__ u16 f2bf(float f) {
  union { float f; u32 u; } v; v.f = f;
  u32 u = v.u;
  u += 0x7fffu + ((u >> 16) & 1u);   // round-to-nearest-even
  return (u16)(u >> 16);
}

__device__ __forceinline__ void async16(const void* g, void* l) {
  __builtin_amdgcn_global_load_lds(
      (const __attribute__((address_space(1))) u32*)g,
      (__attribute__((address_space(3))) u32*)l, 16, 0, 0);
}

// ---------------- fp32 -> bf16 cast (vectorized) ----------------
__global__ __launch_bounds__(256) void cast_f32_bf16(
    const float* __restrict__ in, u16* __restrict__ out, int n4)
{
  int i = blockIdx.x * 256 + threadIdx.x;
  if (i >= n4) return;
  float4 f = ((const float4*)in)[i];
  ushort4 o;
  o.x = f2bf(f.x); o.y = f2bf(f.y); o.z = f2bf(f.z); o.w = f2bf(f.w);
  ((ushort4*)out)[i] = o;
}

// ---------------- bf16 GEMM, C = A[M,K] * B[N,K]^T ----------------
// m97 structure: 128x128 tile, BK=32, 4 waves of 4x4 16x16x32 MFMA tiles,
// global_load_lds width=16 staging, 2-barrier K-loop.
// LDS layout XOR-swizzled to kill ds_read_b128 bank conflicts:
//   slot s holds chunk (row = s>>2, kq = (s&3) ^ ((s>>3)&3)).
// global_load_lds writes lane-contiguous, so the swizzle is applied by
// permuting the GLOBAL source per slot; reads use sq = quad ^ ((l16>>1)&3).
template<bool OUT_BF16>
__global__ __launch_bounds__(256) void gemm_bt(
    const u16* __restrict__ A, const u16* __restrict__ B, void* __restrict__ Cv,
    const int M, const int N, const int K)
{
  __shared__ u16 sA[128 * 32];
  __shared__ u16 sB[128 * 32];

  const int tid  = threadIdx.x;
  const int lane = tid & 63;
  const int wave = tid >> 6;
  const int quad = lane >> 4;
  const int l16  = lane & 15;
  const int wr   = (wave >> 1) * 64;   // wave row offset in tile
  const int wc   = (wave & 1) * 64;    // wave col offset in tile
  const int sq   = quad ^ ((l16 >> 1) & 3);   // swizzled quad for frag reads
  const int mBase = blockIdx.y * 128;
  const int nBase = blockIdx.x * 128;

  // staging: 512 slots of 16B per tile; thread fills slots tid and tid+256.
  // slot s sources global chunk (row = s>>2, kq = (s&3) ^ ((s>>3)&3)).
  const int s0 = tid, s1 = tid + 256;
  const int r0 = s0 >> 2, q0 = (s0 & 3) ^ ((s0 >> 3) & 3);
  const int r1 = s1 >> 2, q1 = (s1 & 3) ^ ((s1 >> 3) & 3);
  const u16* Ag0 = A + (size_t)(mBase + r0) * K + q0 * 8;
  const u16* Ag1 = A + (size_t)(mBase + r1) * K + q1 * 8;
  const u16* Bg0 = B + (size_t)(nBase + r0) * K + q0 * 8;
  const u16* Bg1 = B + (size_t)(nBase + r1) * K + q1 * 8;

  f32x4 zero = {0.f, 0.f, 0.f, 0.f};
  f32x4 acc[4][4];
#pragma unroll
  for (int i = 0; i < 4; ++i)
#pragma unroll
    for (int j = 0; j < 4; ++j) acc[i][j] = zero;

  for (int k0 = 0; k0 < K; k0 += 32) {
    async16(Ag0 + k0, &sA[s0 * 8]);
    async16(Ag1 + k0, &sA[s1 * 8]);
    async16(Bg0 + k0, &sB[s0 * 8]);
    async16(Bg1 + k0, &sB[s1 * 8]);
    __syncthreads();   // compiler emits s_waitcnt vmcnt(0) before s_barrier

    bf16x8 af[4], bfv[4];
#pragma unroll
    for (int t = 0; t < 4; ++t) {
      af[t]  = *(const bf16x8*)&sA[(wr + t * 16 + l16) * 32 + sq * 8];
      bfv[t] = *(const bf16x8*)&sB[(wc + t * 16 + l16) * 32 + sq * 8];
    }
#pragma unroll
    for (int i = 0; i < 4; ++i)
#pragma unroll
      for (int j = 0; j < 4; ++j)
        acc[i][j] = __builtin_amdgcn_mfma_f32_16x16x32_bf16(af[i], bfv[j], acc[i][j], 0, 0, 0);
    __syncthreads();
  }

  // epilogue: C/D layout col=lane&15, row=quad*4+reg  (m89/m91-verified)
#pragma unroll
  for (int i = 0; i < 4; ++i) {
#pragma unroll
    for (int j = 0; j < 4; ++j) {
      const int col = nBase + wc + j * 16 + l16;
#pragma unroll
      for (int r = 0; r < 4; ++r) {
        const int row = mBase + wr + i * 16 + quad * 4 + r;
        if (OUT_BF16)
          ((u16*)Cv)[(size_t)row * N + col] = f2bf(acc[i][j][r]);
        else
          ((float*)Cv)[(size_t)row * N + col] = acc[i][j][r];
      }
    }
  }
}

// ---------------- causal depthwise conv (K=4) + gating ----------------
// bcx: [NTOK, 6144] bf16 (cols: b | c | x). Produces y=[NTOK,2048] bf16 and
// conv states (last 3 bx rows per seq) fp32 into d_out tail.
#define TT 32
__global__ __launch_bounds__(256) void conv_gate(
    const u16* __restrict__ bcx, const float* __restrict__ convw,
    u16* __restrict__ y, float* __restrict__ states)
{
  const int tid = threadIdx.x;
  const int d8  = tid * 8;            // 8 channels per thread, 256 thr = 2048
  const int s   = blockIdx.y;
  const int t0  = blockIdx.x * TT;

  float w0[8], w1[8], w2[8], w3[8];
#pragma unroll
  for (int j = 0; j < 8; ++j) {
    float4 wv = *(const float4*)&convw[(d8 + j) * 4];
    w0[j] = wv.x; w1[j] = wv.y; w2[j] = wv.z; w3[j] = wv.w;
  }

  float win0[8], win1[8], win2[8];    // bx at t-3, t-2, t-1
  if (t0 == 0) {
#pragma unroll
    for (int j = 0; j < 8; ++j) { win0[j] = 0.f; win1[j] = 0.f; win2[j] = 0.f; }
  } else {
    const u16* r0 = bcx + (size_t)(s * SEQ_LEN + t0 - 3) * N3D + d8;
    bf16x8 b0 = *(const bf16x8*)(r0);
    bf16x8 x0 = *(const bf16x8*)(r0 + 2 * CONV_DIM);
    bf16x8 b1 = *(const bf16x8*)(r0 + N3D);
    bf16x8 x1 = *(const bf16x8*)(r0 + N3D + 2 * CONV_DIM);
    bf16x8 b2 = *(const bf16x8*)(r0 + 2 * N3D);
    bf16x8 x2 = *(const bf16x8*)(r0 + 2 * N3D + 2 * CONV_DIM);
#pragma unroll
    for (int j = 0; j < 8; ++j) {
      win0[j] = (float)b0[j] * (float)x0[j];
      win1[j] = (float)b1[j] * (float)x1[j];
      win2[j] = (float)b2[j] * (float)x2[j];
    }
  }

  for (int t = t0; t < t0 + TT; ++t) {
    const u16* row = bcx + (size_t)(s * SEQ_LEN + t) * N3D + d8;
    bf16x8 bv = *(const bf16x8*)row;
    bf16x8 cv = *(const bf16x8*)(row + CONV_DIM);
    bf16x8 xv = *(const bf16x8*)(row + 2 * CONV_DIM);
    float bx[8];
#pragma unroll
    for (int j = 0; j < 8; ++j) bx[j] = (float)bv[j] * (float)xv[j];

    u32 pk[4];
#pragma unroll
    for (int j = 0; j < 4; ++j) {
      const int a = 2 * j, b = 2 * j + 1;
      float ya = (float)cv[a] * (w0[a]*win0[a] + w1[a]*win1[a] + w2[a]*win2[a] + w3[a]*bx[a]);
      float yb = (float)cv[b] * (w0[b]*win0[b] + w1[b]*win1[b] + w2[b]*win2[b] + w3[b]*bx[b]);
      pk[j] = (u32)f2bf(ya) | ((u32)f2bf(yb) << 16);
    }
    uint4 o; o.x = pk[0]; o.y = pk[1]; o.z = pk[2]; o.w = pk[3];
    *(uint4*)&y[(size_t)(s * SEQ_LEN + t) * CONV_DIM + d8] = o;

    if (t >= SEQ_LEN - 3) {
      float* st = states + (size_t)(s * 3 + (t - (SEQ_LEN - 3))) * CONV_DIM + d8;
      float4 s0v; s0v.x = bx[0]; s0v.y = bx[1]; s0v.z = bx[2]; s0v.w = bx[3];
      float4 s1v; s1v.x = bx[4]; s1v.y = bx[5]; s1v.z = bx[6]; s1v.w = bx[7];
      *(float4*)st = s0v;
      *(float4*)(st + 4) = s1v;
    }
#pragma unroll
    for (int j = 0; j < 8; ++j) { win0[j] = win1[j]; win1[j] = win2[j]; win2[j] = bx[j]; }
  }
}

// ---------------- launch ----------------
extern "C" void kernel_launch(void* const* d_in, const int* in_sizes, int n_in,
                              void* d_out, int out_size, void* d_ws, size_t ws_size,
                              hipStream_t stream)
{
  const float* hidden = (const float*)d_in[0];  // [16384, 2048]
  const float* w_in   = (const float*)d_in[1];  // [6144, 2048]
  const float* convw  = (const float*)d_in[2];  // [2048, 1, 4]
  const float* w_out  = (const float*)d_in[3];  // [2048, 2048]

  char* ws = (char*)d_ws;
  u16* hb  = (u16*)(ws);                          // 33554432 elems (67.1 MB)
  u16* wib = (u16*)(ws + (size_t)67108864);       // 12582912 elems (25.2 MB)
  u16* wob = (u16*)(ws + (size_t)92274688);       //  4194304 elems ( 8.4 MB)
  u16* bcx = (u16*)(ws + (size_t)100663296);      // 16384*6144 elems (201 MB)
  u16* yb  = (u16*)(ws + (size_t)301989888);      // 33554432 elems (67.1 MB)

  float* out    = (float*)d_out;                  // [16384, 2048] fp32
  float* states = out + (size_t)NTOK * HIDDEN;    // [4, 3, 2048] fp32

  cast_f32_bf16<<<32768, 256, 0, stream>>>(hidden, hb, 8388608);
  cast_f32_bf16<<<12288, 256, 0, stream>>>(w_in,  wib, 3145728);
  cast_f32_bf16<<<4096,  256, 0, stream>>>(w_out, wob, 1048576);

  // bcx[N,6144] = hidden @ w_in^T  (bf16 out)
  gemm_bt<true><<<dim3(N3D / 128, NTOK / 128), 256, 0, stream>>>(
      hb, wib, bcx, NTOK, N3D, HIDDEN);

  // depthwise conv + gates -> y bf16, states fp32
  conv_gate<<<dim3(SEQ_LEN / TT, NUM_SEQS), 256, 0, stream>>>(bcx, convw, yb, states);

  // out[N,2048] = y @ w_out^T  (fp32 out)
  gemm_bt<false><<<dim3(CONV_DIM / 128, NTOK / 128), 256, 0, stream>>>(
      yb, wob, out, NTOK, CONV_DIM, CONV_DIM);
}

// Round 3
// 977.900 us; speedup vs baseline: 1.0610x; 1.0582x over previous
//
#include <hip/hip_runtime.h>
#include <stdint.h>

#define NUM_SEQS 4
#define SEQ_LEN  4096
#define HIDDEN   2048
#define CONV_DIM 2048
#define NTOK     (NUM_SEQS * SEQ_LEN)
#define N3D      (3 * CONV_DIM)

typedef unsigned short u16;
typedef unsigned int   u32;
typedef __bf16 bf16x8 __attribute__((ext_vector_type(8)));
typedef float  f32x16 __attribute__((ext_vector_type(16)));

__device__ __forceinline__ u16 f2bf(float f) {
  union { float f; u32 u; } v; v.f = f;
  u32 u = v.u;
  u += 0x7fffu + ((u >> 16) & 1u);   // round-to-nearest-even
  return (u16)(u >> 16);
}

__device__ __forceinline__ void async16(const void* g, void* l) {
  __builtin_amdgcn_global_load_lds(
      (const __attribute__((address_space(1))) u32*)g,
      (__attribute__((address_space(3))) u32*)l, 16, 0, 0);
}

// ---------------- fp32 -> bf16 cast (vectorized) ----------------
__global__ __launch_bounds__(256) void cast_f32_bf16(
    const float* __restrict__ in, u16* __restrict__ out, int n4)
{
  int i = blockIdx.x * 256 + threadIdx.x;
  if (i >= n4) return;
  float4 f = ((const float4*)in)[i];
  ushort4 o;
  o.x = f2bf(f.x); o.y = f2bf(f.y); o.z = f2bf(f.z); o.w = f2bf(f.w);
  ((ushort4*)out)[i] = o;
}

// ---------------- bf16 GEMM, C = A[M,K] * B[N,K]^T ----------------
// 128x128 tile, BK=32, 4 waves each computing a 64x64 region as 2x2 tiles of
// v_mfma_f32_32x32x16_bf16 (2382 TF ubench vs 2075 for 16x16x32 — m06).
// A-frag: A[m=lane&31][k=8*(lane>>5)+j]  (contiguous-8 analog of verified
// 16x16x32 layout). C/D: col=lane&31, row=(reg&3)+8*(reg>>2)+4*(lane>>5)
// (m74/m101-verified).
// LDS slot swizzle (kills ds_read_b128 bank conflicts for 32-row frag reads):
//   chunk (row r, k-chunk c) lives at slot 4r + (c ^ ((r>>1)&3)).
//   granule = slot mod 8 covers all 8 bank-groups per 8 consecutive lanes.
// global_load_lds writes lane-contiguous, so the swizzle is applied by
// permuting the GLOBAL source chunk per slot.
template<bool OUT_BF16>
__global__ __launch_bounds__(256) void gemm_bt(
    const u16* __restrict__ A, const u16* __restrict__ B, void* __restrict__ Cv,
    const int M, const int N, const int K)
{
  __shared__ u16 sA[128 * 32];
  __shared__ u16 sB[128 * 32];

  const int tid  = threadIdx.x;
  const int lane = tid & 63;
  const int wave = tid >> 6;
  const int l32  = lane & 31;
  const int half = lane >> 5;
  const int wr   = (wave >> 1) * 64;   // wave row offset in tile
  const int wc   = (wave & 1) * 64;    // wave col offset in tile
  const int mBase = blockIdx.y * 128;
  const int nBase = blockIdx.x * 128;

  // staging: 512 slots of 16B per tile; thread fills slots tid and tid+256.
  // slot s holds global chunk (r = s>>2, c = (s&3) ^ ((r>>1)&3)).
  const int s0 = tid, s1 = tid + 256;
  const int r0 = s0 >> 2, c0 = (s0 & 3) ^ ((r0 >> 1) & 3);
  const int r1 = s1 >> 2, c1 = (s1 & 3) ^ ((r1 >> 1) & 3);
  const u16* Ag0 = A + (size_t)(mBase + r0) * K + c0 * 8;
  const u16* Ag1 = A + (size_t)(mBase + r1) * K + c1 * 8;
  const u16* Bg0 = B + (size_t)(nBase + r0) * K + c0 * 8;
  const u16* Bg1 = B + (size_t)(nBase + r1) * K + c1 * 8;

  // fragment-read LDS slots (loop-invariant): tile row r, chunk c = kt*2+half
  int aslot[2][2], bslot[2][2];   // [mt or nt][kt]
#pragma unroll
  for (int mt = 0; mt < 2; ++mt) {
#pragma unroll
    for (int kt = 0; kt < 2; ++kt) {
      const int ra = wr + mt * 32 + l32;
      const int rb = wc + mt * 32 + l32;
      const int c  = kt * 2 + half;
      aslot[mt][kt] = 4 * ra + (c ^ ((ra >> 1) & 3));
      bslot[mt][kt] = 4 * rb + (c ^ ((rb >> 1) & 3));
    }
  }

  f32x16 acc[2][2];
#pragma unroll
  for (int i = 0; i < 2; ++i)
#pragma unroll
    for (int j = 0; j < 2; ++j)
#pragma unroll
      for (int r = 0; r < 16; ++r) acc[i][j][r] = 0.f;

  for (int k0 = 0; k0 < K; k0 += 32) {
    async16(Ag0 + k0, &sA[s0 * 8]);
    async16(Ag1 + k0, &sA[s1 * 8]);
    async16(Bg0 + k0, &sB[s0 * 8]);
    async16(Bg1 + k0, &sB[s1 * 8]);
    __syncthreads();   // compiler emits s_waitcnt vmcnt(0) before s_barrier

    bf16x8 af[2][2], bfv[2][2];
#pragma unroll
    for (int mt = 0; mt < 2; ++mt)
#pragma unroll
      for (int kt = 0; kt < 2; ++kt) {
        af[mt][kt]  = *(const bf16x8*)&sA[aslot[mt][kt] * 8];
        bfv[mt][kt] = *(const bf16x8*)&sB[bslot[mt][kt] * 8];
      }
#pragma unroll
    for (int kt = 0; kt < 2; ++kt)
#pragma unroll
      for (int mt = 0; mt < 2; ++mt)
#pragma unroll
        for (int nt = 0; nt < 2; ++nt)
          acc[mt][nt] = __builtin_amdgcn_mfma_f32_32x32x16_bf16(
              af[mt][kt], bfv[nt][kt], acc[mt][nt], 0, 0, 0);
    __syncthreads();
  }

  // epilogue: C/D layout col=lane&31, row=(reg&3)+8*(reg>>2)+4*(lane>>5)
#pragma unroll
  for (int mt = 0; mt < 2; ++mt) {
#pragma unroll
    for (int nt = 0; nt < 2; ++nt) {
      const int col = nBase + wc + nt * 32 + l32;
#pragma unroll
      for (int r = 0; r < 16; ++r) {
        const int row = mBase + wr + mt * 32 + (r & 3) + 8 * (r >> 2) + 4 * half;
        if (OUT_BF16)
          ((u16*)Cv)[(size_t)row * N + col] = f2bf(acc[mt][nt][r]);
        else
          ((float*)Cv)[(size_t)row * N + col] = acc[mt][nt][r];
      }
    }
  }
}

// ---------------- causal depthwise conv (K=4) + gating ----------------
// bcx: [NTOK, 6144] bf16 (cols: b | c | x). Produces y=[NTOK,2048] bf16 and
// conv states (last 3 bx rows per seq) fp32 into d_out tail.
#define TT 32
__global__ __launch_bounds__(256) void conv_gate(
    const u16* __restrict__ bcx, const float* __restrict__ convw,
    u16* __restrict__ y, float* __restrict__ states)
{
  const int tid = threadIdx.x;
  const int d8  = tid * 8;            // 8 channels per thread, 256 thr = 2048
  const int s   = blockIdx.y;
  const int t0  = blockIdx.x * TT;

  float w0[8], w1[8], w2[8], w3[8];
#pragma unroll
  for (int j = 0; j < 8; ++j) {
    float4 wv = *(const float4*)&convw[(d8 + j) * 4];
    w0[j] = wv.x; w1[j] = wv.y; w2[j] = wv.z; w3[j] = wv.w;
  }

  float win0[8], win1[8], win2[8];    // bx at t-3, t-2, t-1
  if (t0 == 0) {
#pragma unroll
    for (int j = 0; j < 8; ++j) { win0[j] = 0.f; win1[j] = 0.f; win2[j] = 0.f; }
  } else {
    const u16* r0 = bcx + (size_t)(s * SEQ_LEN + t0 - 3) * N3D + d8;
    bf16x8 b0 = *(const bf16x8*)(r0);
    bf16x8 x0 = *(const bf16x8*)(r0 + 2 * CONV_DIM);
    bf16x8 b1 = *(const bf16x8*)(r0 + N3D);
    bf16x8 x1 = *(const bf16x8*)(r0 + N3D + 2 * CONV_DIM);
    bf16x8 b2 = *(const bf16x8*)(r0 + 2 * N3D);
    bf16x8 x2 = *(const bf16x8*)(r0 + 2 * N3D + 2 * CONV_DIM);
#pragma unroll
    for (int j = 0; j < 8; ++j) {
      win0[j] = (float)b0[j] * (float)x0[j];
      win1[j] = (float)b1[j] * (float)x1[j];
      win2[j] = (float)b2[j] * (float)x2[j];
    }
  }

  for (int t = t0; t < t0 + TT; ++t) {
    const u16* row = bcx + (size_t)(s * SEQ_LEN + t) * N3D + d8;
    bf16x8 bv = *(const bf16x8*)row;
    bf16x8 cv = *(const bf16x8*)(row + CONV_DIM);
    bf16x8 xv = *(const bf16x8*)(row + 2 * CONV_DIM);
    float bx[8];
#pragma unroll
    for (int j = 0; j < 8; ++j) bx[j] = (float)bv[j] * (float)xv[j];

    u32 pk[4];
#pragma unroll
    for (int j = 0; j < 4; ++j) {
      const int a = 2 * j, b = 2 * j + 1;
      float ya = (float)cv[a] * (w0[a]*win0[a] + w1[a]*win1[a] + w2[a]*win2[a] + w3[a]*bx[a]);
      float yb = (float)cv[b] * (w0[b]*win0[b] + w1[b]*win1[b] + w2[b]*win2[b] + w3[b]*bx[b]);
      pk[j] = (u32)f2bf(ya) | ((u32)f2bf(yb) << 16);
    }
    uint4 o; o.x = pk[0]; o.y = pk[1]; o.z = pk[2]; o.w = pk[3];
    *(uint4*)&y[(size_t)(s * SEQ_LEN + t) * CONV_DIM + d8] = o;

    if (t >= SEQ_LEN - 3) {
      float* st = states + (size_t)(s * 3 + (t - (SEQ_LEN - 3))) * CONV_DIM + d8;
      float4 s0v; s0v.x = bx[0]; s0v.y = bx[1]; s0v.z = bx[2]; s0v.w = bx[3];
      float4 s1v; s1v.x = bx[4]; s1v.y = bx[5]; s1v.z = bx[6]; s1v.w = bx[7];
      *(float4*)st = s0v;
      *(float4*)(st + 4) = s1v;
    }
#pragma unroll
    for (int j = 0; j < 8; ++j) { win0[j] = win1[j]; win1[j] = win2[j]; win2[j] = bx[j]; }
  }
}

// ---------------- launch ----------------
extern "C" void kernel_launch(void* const* d_in, const int* in_sizes, int n_in,
                              void* d_out, int out_size, void* d_ws, size_t ws_size,
                              hipStream_t stream)
{
  const float* hidden = (const float*)d_in[0];  // [16384, 2048]
  const float* w_in   = (const float*)d_in[1];  // [6144, 2048]
  const float* convw  = (const float*)d_in[2];  // [2048, 1, 4]
  const float* w_out  = (const float*)d_in[3];  // [2048, 2048]

  char* ws = (char*)d_ws;
  u16* hb  = (u16*)(ws);                          // 33554432 elems (67.1 MB)
  u16* wib = (u16*)(ws + (size_t)67108864);       // 12582912 elems (25.2 MB)
  u16* wob = (u16*)(ws + (size_t)92274688);       //  4194304 elems ( 8.4 MB)
  u16* bcx = (u16*)(ws + (size_t)100663296);      // 16384*6144 elems (201 MB)
  u16* yb  = (u16*)(ws + (size_t)301989888);      // 33554432 elems (67.1 MB)

  float* out    = (float*)d_out;                  // [16384, 2048] fp32
  float* states = out + (size_t)NTOK * HIDDEN;    // [4, 3, 2048] fp32

  cast_f32_bf16<<<32768, 256, 0, stream>>>(hidden, hb, 8388608);
  cast_f32_bf16<<<12288, 256, 0, stream>>>(w_in,  wib, 3145728);
  cast_f32_bf16<<<4096,  256, 0, stream>>>(w_out, wob, 1048576);

  // bcx[N,6144] = hidden @ w_in^T  (bf16 out)
  gemm_bt<true><<<dim3(N3D / 128, NTOK / 128), 256, 0, stream>>>(
      hb, wib, bcx, NTOK, N3D, HIDDEN);

  // depthwise conv + gates -> y bf16, states fp32
  conv_gate<<<dim3(SEQ_LEN / TT, NUM_SEQS), 256, 0, stream>>>(bcx, convw, yb, states);

  // out[N,2048] = y @ w_out^T  (fp32 out)
  gemm_bt<false><<<dim3(CONV_DIM / 128, NTOK / 128), 256, 0, stream>>>(
      yb, wob, out, NTOK, CONV_DIM, CONV_DIM);
}